// Round 6
// baseline (351.796 us; speedup 1.0000x reference)
//
#include <hip/hip_runtime.h>

// Ultimus: out = x + softmax((x@Kw+Kb)@(x@Qw+Qb)^T / sqrt(8)) @ (x@Vw+Vb) @ Zw + Zb
// N=8192, D_IN=48, D_ATTN=8, fp32 in/out.
//
// R6: row-per-lane attention. R5's 64-lane butterfly (432 ds_swizzle/wave)
// was DS-pipe-bound (~33 us of LDS occupancy/CU). Now each lane owns ONE
// row's accumulators privately; j is a wave-uniform loop so Q/V come in via
// s_load (scalar pipe), and partials merge via global_atomic_add_f32.
// No LDS, no shfl, no barriers anywhere in attn.
//
//  - Bound-softmax (Cauchy-Schwarz row bound) => fixed per-row exponent
//    shift; per-chunk partials combine by pure addition (atomicAdd).
//  - f16 storage + v_dot2_f32_f16 with one SGPR operand (q/v) per dot.
//
// ws layout (floats):
//   [0, 32768)        Xksf16[8192]   8 f16/row (k * log2e/sqrt(8)), uint4/row
//   [32768, 98304)    QV             per j-pair p: 16 dwords =
//                                    q[2p](4) | q[2p+1](4) | vpair(8), where
//                                    vpair dword c = half2(V[2p][c],V[2p+1][c])
//   [98304]           qmax2 bits     max_j ||q_j||^2 fp32 (uint atomicMax)
//   [98560, +131072)  accG[8192][16] fp32: acc[0:8], l at [8] (atomicAdd)

#define QV_OFF   32768
#define QMAX_OFF 98304
#define ACC_OFF  98560

typedef _Float16 f16x2 __attribute__((ext_vector_type(2)));

union HU { unsigned u; f16x2 h; };

static __device__ __forceinline__ unsigned pku(float a, float b) {
    auto v = __builtin_amdgcn_cvt_pkrtz(a, b);   // __fp16 vec2
    union { decltype(v) v2; unsigned u; } t;
    t.v2 = v;
    return t.u;
}
static __device__ __forceinline__ f16x2 asH2(unsigned u) {
    HU t; t.u = u; return t.h;
}
static __device__ __forceinline__ float fdot2(f16x2 a, f16x2 b, float c) {
#if __has_builtin(__builtin_amdgcn_fdot2)
    return __builtin_amdgcn_fdot2(a, b, c, false);
#else
    return fmaf((float)a.x, (float)b.x, fmaf((float)a.y, (float)b.y, c));
#endif
}

__global__ __launch_bounds__(256) void proj_kernel(
    const float* __restrict__ x,
    const float* __restrict__ Kw, const float* __restrict__ Kb,
    const float* __restrict__ Qw, const float* __restrict__ Qb,
    const float* __restrict__ Vw, const float* __restrict__ Vb,
    unsigned* __restrict__ Xksf16, unsigned* __restrict__ QV,
    unsigned int* __restrict__ qmax2_bits)
{
    __shared__ float xs[32 * 49];     // +1 pad
    __shared__ float wAll[3 * 388];   // stride 388 (mod 32 = 4) spreads 3 mats
    __shared__ float bs[24];
    __shared__ float outv[32][25];    // 24 cols + pad
    const int tid = threadIdx.x;
    const int r0 = blockIdx.x * 32;

    for (int i = tid; i < 1536; i += 256) {
        int r = i / 48, c = i - r * 48;
        xs[r * 49 + c] = x[r0 * 48 + i];
    }
    for (int i = tid; i < 384; i += 256) {
        wAll[i]       = Kw[i];
        wAll[388 + i] = Qw[i];
        wAll[776 + i] = Vw[i];
    }
    if (tid < 8)       bs[tid] = Kb[tid];
    else if (tid < 16) bs[tid] = Qb[tid - 8];
    else if (tid < 24) bs[tid] = Vb[tid - 16];
    __syncthreads();

    // thread = (row rl, col-group g): cols 3g..3g+2 of row r0+rl
    const int rl = tid >> 3;
    const int g  = tid & 7;
    const int c0 = 3 * g;
    const float* xr = &xs[rl * 49];
    const float* w0 = &wAll[((c0 + 0) >> 3) * 388 + ((c0 + 0) & 7)];
    const float* w1 = &wAll[((c0 + 1) >> 3) * 388 + ((c0 + 1) & 7)];
    const float* w2 = &wAll[((c0 + 2) >> 3) * 388 + ((c0 + 2) & 7)];
    float a0 = bs[c0], a1 = bs[c0 + 1], a2 = bs[c0 + 2];
    #pragma unroll
    for (int k = 0; k < 48; k++) {
        const float xv = xr[k];
        a0 = fmaf(xv, w0[k * 8], a0);
        a1 = fmaf(xv, w1[k * 8], a1);
        a2 = fmaf(xv, w2[k * 8], a2);
    }
    outv[rl][c0] = a0; outv[rl][c0 + 1] = a1; outv[rl][c0 + 2] = a2;
    __syncthreads();

    const float kscale = 0.51008732149f;  // (1/sqrt(8)) * log2(e)
    if (tid < 32) {                       // K rows, f16 packed, pre-scaled
        uint4 o;
        o.x = pku(outv[tid][0] * kscale, outv[tid][1] * kscale);
        o.y = pku(outv[tid][2] * kscale, outv[tid][3] * kscale);
        o.z = pku(outv[tid][4] * kscale, outv[tid][5] * kscale);
        o.w = pku(outv[tid][6] * kscale, outv[tid][7] * kscale);
        ((uint4*)Xksf16)[r0 + tid] = o;
    } else if (tid < 64) {                // Q rows -> QV slot (pair p, j&1)
        const int r = tid - 32;
        const int j = r0 + r;
        uint4 o;
        o.x = pku(outv[r][8],  outv[r][9]);
        o.y = pku(outv[r][10], outv[r][11]);
        o.z = pku(outv[r][12], outv[r][13]);
        o.w = pku(outv[r][14], outv[r][15]);
        ((uint4*)QV)[(j >> 1) * 4 + (j & 1)] = o;
    } else if (tid < 192) {               // V pair-interleaved -> QV dwords 8..15
        const int t2 = tid - 64;
        const int p = t2 >> 3, c = t2 & 7;
        const int pg = blockIdx.x * 16 + p;
        QV[pg * 16 + 8 + c] = pku(outv[2 * p][16 + c], outv[2 * p + 1][16 + c]);
    } else if (tid < 224) {               // qmax over fp32 q (lanes 0..31 of wave 3)
        const int r = tid - 192;
        float n2 = 0.f;
        #pragma unroll
        for (int c = 0; c < 8; c++) n2 = fmaf(outv[r][8 + c], outv[r][8 + c], n2);
        #pragma unroll
        for (int off = 16; off > 0; off >>= 1)
            n2 = fmaxf(n2, __shfl_xor(n2, off, 64));
        if (r == 0) atomicMax(qmax2_bits, __float_as_uint(n2));  // n2>=0: bit order ok
    }
}

// grid = 32 row-groups (256 rows, 4 waves x 64 lanes) x 64 j-chunks (64 pairs)
__global__ __launch_bounds__(256) void attn_kernel(
    const unsigned* __restrict__ Xksf16, const unsigned* __restrict__ QV,
    const unsigned int* __restrict__ qmax2_bits,
    float* __restrict__ accG)
{
    const int tid   = threadIdx.x;
    const int wave  = tid >> 6, lane = tid & 63;
    const int rgrp  = blockIdx.x & 31;    // 256-row group
    const int chunk = blockIdx.x >> 5;    // 64 chunks x 64 pairs (128 j)
    const int row   = rgrp * 256 + wave * 64 + lane;

    const float qmax2 = __uint_as_float(*qmax2_bits);

    const uint4 kv = ((const uint4*)Xksf16)[row];   // coalesced 16B/lane
    f16x2 k2[4] = {asH2(kv.x), asH2(kv.y), asH2(kv.z), asH2(kv.w)};
    float kn2 = fdot2(k2[0], k2[0], 0.f);
    kn2 = fdot2(k2[1], k2[1], kn2);
    kn2 = fdot2(k2[2], k2[2], kn2);
    kn2 = fdot2(k2[3], k2[3], kn2);
    const float sinit = -sqrtf(kn2 * qmax2);  // s <= -sinit: p in (0,~1]

    float l = 0.f, acc[8];
    #pragma unroll
    for (int c = 0; c < 8; c++) acc[c] = 0.f;

    const f16x2 one2 = asH2(0x3C003C00u);     // (1.0h, 1.0h)
    // wave-uniform pointer: all indices below are lane-invariant -> s_load
    const uint4* QV4 = (const uint4*)QV + (size_t)chunk * 64 * 4;

    #pragma unroll 4
    for (int p = 0; p < 64; p++) {
        const uint4 qa = QV4[p * 4 + 0];      // q[2p]
        const uint4 qb = QV4[p * 4 + 1];      // q[2p+1]
        const uint4 va = QV4[p * 4 + 2];      // vpair dwords 0..3
        const uint4 vb = QV4[p * 4 + 3];      // vpair dwords 4..7
        float s0 = fdot2(k2[0], asH2(qa.x), sinit);
        s0 = fdot2(k2[1], asH2(qa.y), s0);
        s0 = fdot2(k2[2], asH2(qa.z), s0);
        s0 = fdot2(k2[3], asH2(qa.w), s0);
        float s1 = fdot2(k2[0], asH2(qb.x), sinit);
        s1 = fdot2(k2[1], asH2(qb.y), s1);
        s1 = fdot2(k2[2], asH2(qb.z), s1);
        s1 = fdot2(k2[3], asH2(qb.w), s1);
        const f16x2 ph = asH2(pku(__builtin_amdgcn_exp2f(s0),
                                  __builtin_amdgcn_exp2f(s1)));
        l = fdot2(ph, one2, l);
        acc[0] = fdot2(ph, asH2(va.x), acc[0]);
        acc[1] = fdot2(ph, asH2(va.y), acc[1]);
        acc[2] = fdot2(ph, asH2(va.z), acc[2]);
        acc[3] = fdot2(ph, asH2(va.w), acc[3]);
        acc[4] = fdot2(ph, asH2(vb.x), acc[4]);
        acc[5] = fdot2(ph, asH2(vb.y), acc[5]);
        acc[6] = fdot2(ph, asH2(vb.z), acc[6]);
        acc[7] = fdot2(ph, asH2(vb.w), acc[7]);
    }

    float* dst = accG + (size_t)row * 16;
    #pragma unroll
    for (int c = 0; c < 8; c++) atomicAdd(dst + c, acc[c]);
    atomicAdd(dst + 8, l);
}

__global__ __launch_bounds__(256) void finish_kernel(
    const float* __restrict__ x,
    const float* __restrict__ Zw, const float* __restrict__ Zb,
    const float* __restrict__ accG, float* __restrict__ out)
{
    __shared__ float Zs[128 * 9];
    __shared__ float zw_s[384];
    __shared__ float zb_s[48];
    const int tid = threadIdx.x;
    const int r0 = blockIdx.x * 128;

    for (int i = tid; i < 384; i += 256) zw_s[i] = Zw[i];
    if (tid < 48) zb_s[tid] = Zb[tid];

    if (tid < 128) {
        const int row = r0 + tid;
        const float* a = accG + (size_t)row * 16;
        const float inv = 1.0f / a[8];
        #pragma unroll
        for (int c = 0; c < 8; c++) Zs[tid * 9 + c] = a[c] * inv;
    }
    __syncthreads();

    for (int e = tid; e < 128 * 48; e += 256) {
        const int r = e / 48, c = e - r * 48;
        float o = x[r0 * 48 + e] + zb_s[c];
        #pragma unroll
        for (int k = 0; k < 8; k++) o = fmaf(Zs[r * 9 + k], zw_s[k * 48 + c], o);
        out[r0 * 48 + e] = o;
    }
}

extern "C" void kernel_launch(void* const* d_in, const int* in_sizes, int n_in,
                              void* d_out, int out_size, void* d_ws, size_t ws_size,
                              hipStream_t stream) {
    const float* x  = (const float*)d_in[0];
    const float* Kw = (const float*)d_in[1];
    const float* Kb = (const float*)d_in[2];
    const float* Qw = (const float*)d_in[3];
    const float* Qb = (const float*)d_in[4];
    const float* Vw = (const float*)d_in[5];
    const float* Vb = (const float*)d_in[6];
    const float* Zw = (const float*)d_in[7];
    const float* Zb = (const float*)d_in[8];
    float* out = (float*)d_out;

    float* ws = (float*)d_ws;
    unsigned* Xksf16 = (unsigned*)ws;
    unsigned* QV     = (unsigned*)(ws + QV_OFF);
    unsigned int* qmax2_bits = (unsigned int*)(ws + QMAX_OFF);
    float* accG = ws + ACC_OFF;

    (void)hipMemsetAsync(qmax2_bits, 0, sizeof(unsigned int), stream);
    (void)hipMemsetAsync(accG, 0, 8192 * 16 * sizeof(float), stream);
    proj_kernel<<<256, 256, 0, stream>>>(x, Kw, Kb, Qw, Qb, Vw, Vb,
                                         Xksf16, QV, qmax2_bits);
    attn_kernel<<<2048, 256, 0, stream>>>(Xksf16, QV, qmax2_bits, accG);
    finish_kernel<<<64, 256, 0, stream>>>(x, Zw, Zb, accG, out);
}

// Round 7
// 119.054 us; speedup vs baseline: 2.9549x; 2.9549x over previous
//
#include <hip/hip_runtime.h>

// Ultimus: out = x + softmax((x@Kw+Kb)@(x@Qw+Qb)^T / sqrt(8)) @ (x@Vw+Vb) @ Zw + Zb
// N=8192, D_IN=48, D_ATTN=8, fp32 in/out.
//
// R7: row-per-lane attention with PLAIN-STORE partial merge.
// R6 post-mortem: 4.7M global fp32 atomicAdds wrote through to HBM
// (WRITE_SIZE 147 MB -> 270 us). The loop structure was right (scalar-pipe
// Q/V loads, private per-lane accumulators, no shfl/LDS in loop); only the
// merge was wrong. Now: 4 waves/block share 64 rows (row = lane), each wave
// a different j-slice; one end-of-kernel LDS reduce (once, ~9 ds ops/lane),
// coalesced fp32 partial stores; finish kernel sums the j-chunks.
//
//  - Bound-softmax (Cauchy-Schwarz row bound) => fixed per-row exponent
//    shift; partials over disjoint j-chunks combine by pure addition.
//  - f16 storage + v_dot2_f32_f16, q/v operands from SGPRs (s_load_dwordx16).
//
// ws layout (floats):
//   [0, 32768)        Xksf16[8192]   8 f16/row (k * log2e/sqrt(8)), uint4/row
//   [32768, 98304)    QV             per j-pair p: 16 dwords =
//                                    q[2p](4) | q[2p+1](4) | vpair(8), where
//                                    vpair dword c = half2(V[2p][c],V[2p+1][c])
//   [98304]           qmax2 bits     max_j ||q_j||^2 fp32 (uint atomicMax)
//   [98560, ...)      part[nch][8192][9]  fp32 partials: acc[0:8], l at [8]

#define QV_OFF   32768
#define QMAX_OFF 98304
#define PART_OFF 98560

typedef _Float16 f16x2 __attribute__((ext_vector_type(2)));

union HU { unsigned u; f16x2 h; };

static __device__ __forceinline__ unsigned pku(float a, float b) {
    auto v = __builtin_amdgcn_cvt_pkrtz(a, b);   // __fp16 vec2
    union { decltype(v) v2; unsigned u; } t;
    t.v2 = v;
    return t.u;
}
static __device__ __forceinline__ f16x2 asH2(unsigned u) {
    HU t; t.u = u; return t.h;
}
static __device__ __forceinline__ float fdot2(f16x2 a, f16x2 b, float c) {
#if __has_builtin(__builtin_amdgcn_fdot2)
    return __builtin_amdgcn_fdot2(a, b, c, false);
#else
    return fmaf((float)a.x, (float)b.x, fmaf((float)a.y, (float)b.y, c));
#endif
}

__global__ __launch_bounds__(256) void proj_kernel(
    const float* __restrict__ x,
    const float* __restrict__ Kw, const float* __restrict__ Kb,
    const float* __restrict__ Qw, const float* __restrict__ Qb,
    const float* __restrict__ Vw, const float* __restrict__ Vb,
    unsigned* __restrict__ Xksf16, unsigned* __restrict__ QV,
    unsigned int* __restrict__ qmax2_bits)
{
    __shared__ float xs[32 * 49];     // +1 pad
    __shared__ float wAll[3 * 388];   // stride 388 (mod 32 = 4) spreads 3 mats
    __shared__ float bs[24];
    __shared__ float outv[32][25];    // 24 cols + pad
    const int tid = threadIdx.x;
    const int r0 = blockIdx.x * 32;

    for (int i = tid; i < 1536; i += 256) {
        int r = i / 48, c = i - r * 48;
        xs[r * 49 + c] = x[r0 * 48 + i];
    }
    for (int i = tid; i < 384; i += 256) {
        wAll[i]       = Kw[i];
        wAll[388 + i] = Qw[i];
        wAll[776 + i] = Vw[i];
    }
    if (tid < 8)       bs[tid] = Kb[tid];
    else if (tid < 16) bs[tid] = Qb[tid - 8];
    else if (tid < 24) bs[tid] = Vb[tid - 16];
    __syncthreads();

    // thread = (row rl, col-group g): cols 3g..3g+2 of row r0+rl
    const int rl = tid >> 3;
    const int g  = tid & 7;
    const int c0 = 3 * g;
    const float* xr = &xs[rl * 49];
    const float* w0 = &wAll[((c0 + 0) >> 3) * 388 + ((c0 + 0) & 7)];
    const float* w1 = &wAll[((c0 + 1) >> 3) * 388 + ((c0 + 1) & 7)];
    const float* w2 = &wAll[((c0 + 2) >> 3) * 388 + ((c0 + 2) & 7)];
    float a0 = bs[c0], a1 = bs[c0 + 1], a2 = bs[c0 + 2];
    #pragma unroll
    for (int k = 0; k < 48; k++) {
        const float xv = xr[k];
        a0 = fmaf(xv, w0[k * 8], a0);
        a1 = fmaf(xv, w1[k * 8], a1);
        a2 = fmaf(xv, w2[k * 8], a2);
    }
    outv[rl][c0] = a0; outv[rl][c0 + 1] = a1; outv[rl][c0 + 2] = a2;
    __syncthreads();

    const float kscale = 0.51008732149f;  // (1/sqrt(8)) * log2(e)
    if (tid < 32) {                       // K rows, f16 packed, pre-scaled
        uint4 o;
        o.x = pku(outv[tid][0] * kscale, outv[tid][1] * kscale);
        o.y = pku(outv[tid][2] * kscale, outv[tid][3] * kscale);
        o.z = pku(outv[tid][4] * kscale, outv[tid][5] * kscale);
        o.w = pku(outv[tid][6] * kscale, outv[tid][7] * kscale);
        ((uint4*)Xksf16)[r0 + tid] = o;
    } else if (tid < 64) {                // Q rows -> QV slot (pair p, j&1)
        const int r = tid - 32;
        const int j = r0 + r;
        uint4 o;
        o.x = pku(outv[r][8],  outv[r][9]);
        o.y = pku(outv[r][10], outv[r][11]);
        o.z = pku(outv[r][12], outv[r][13]);
        o.w = pku(outv[r][14], outv[r][15]);
        ((uint4*)QV)[(j >> 1) * 4 + (j & 1)] = o;
    } else if (tid < 192) {               // V pair-interleaved -> QV dwords 8..15
        const int t2 = tid - 64;
        const int p = t2 >> 3, c = t2 & 7;
        const int pg = blockIdx.x * 16 + p;
        QV[pg * 16 + 8 + c] = pku(outv[2 * p][16 + c], outv[2 * p + 1][16 + c]);
    } else if (tid < 224) {               // qmax over fp32 q (lanes 0..31 of wave 3)
        const int r = tid - 192;
        float n2 = 0.f;
        #pragma unroll
        for (int c = 0; c < 8; c++) n2 = fmaf(outv[r][8 + c], outv[r][8 + c], n2);
        #pragma unroll
        for (int off = 16; off > 0; off >>= 1)
            n2 = fmaxf(n2, __shfl_xor(n2, off, 64));
        if (r == 0) atomicMax(qmax2_bits, __float_as_uint(n2));  // n2>=0: bit order ok
    }
}

// grid = 128 row-groups (64 rows; row = lane) x nch j-chunks.
// Wave w of a block handles pairs [chunk*4*ppw + w*ppw, +ppw).
__global__ __launch_bounds__(256) void attn_kernel(
    const unsigned* __restrict__ Xksf16, const unsigned* __restrict__ QV,
    const unsigned int* __restrict__ qmax2_bits,
    float* __restrict__ part, int ppw)
{
    __shared__ float red[4][64][13];   // stride 13: conflict-free lane writes
    const int tid  = threadIdx.x;
    const int lane = tid & 63;
    const int wv   = __builtin_amdgcn_readfirstlane(tid >> 6);  // provably uniform
    const int rgrp  = blockIdx.x & 127;
    const int chunk = blockIdx.x >> 7;
    const int row   = rgrp * 64 + lane;

    const float qmax2 = __uint_as_float(*qmax2_bits);

    const uint4 kv = ((const uint4*)Xksf16)[row];   // coalesced 16B/lane
    f16x2 k2[4] = {asH2(kv.x), asH2(kv.y), asH2(kv.z), asH2(kv.w)};
    float kn2 = fdot2(k2[0], k2[0], 0.f);
    kn2 = fdot2(k2[1], k2[1], kn2);
    kn2 = fdot2(k2[2], k2[2], kn2);
    kn2 = fdot2(k2[3], k2[3], kn2);
    const float sinit = -sqrtf(kn2 * qmax2);  // s <= -sinit: p in (0,~1]

    float l = 0.f, acc[8];
    #pragma unroll
    for (int c = 0; c < 8; c++) acc[c] = 0.f;

    const f16x2 one2 = asH2(0x3C003C00u);     // (1.0h, 1.0h)
    // wave-uniform pointer -> s_load_dwordx16 per pair (scalar pipe)
    const uint4* QV4 = (const uint4*)QV + ((size_t)(chunk * 4 + wv) * ppw) * 4;

    #pragma unroll 4
    for (int p = 0; p < ppw; p++) {
        const uint4 qa = QV4[p * 4 + 0];      // q[2p]
        const uint4 qb = QV4[p * 4 + 1];      // q[2p+1]
        const uint4 va = QV4[p * 4 + 2];      // vpair dwords 0..3
        const uint4 vb = QV4[p * 4 + 3];      // vpair dwords 4..7
        float s0 = fdot2(k2[0], asH2(qa.x), sinit);
        s0 = fdot2(k2[1], asH2(qa.y), s0);
        s0 = fdot2(k2[2], asH2(qa.z), s0);
        s0 = fdot2(k2[3], asH2(qa.w), s0);
        float s1 = fdot2(k2[0], asH2(qb.x), sinit);
        s1 = fdot2(k2[1], asH2(qb.y), s1);
        s1 = fdot2(k2[2], asH2(qb.z), s1);
        s1 = fdot2(k2[3], asH2(qb.w), s1);
        const f16x2 ph = asH2(pku(__builtin_amdgcn_exp2f(s0),
                                  __builtin_amdgcn_exp2f(s1)));
        l = fdot2(ph, one2, l);
        acc[0] = fdot2(ph, asH2(va.x), acc[0]);
        acc[1] = fdot2(ph, asH2(va.y), acc[1]);
        acc[2] = fdot2(ph, asH2(va.z), acc[2]);
        acc[3] = fdot2(ph, asH2(va.w), acc[3]);
        acc[4] = fdot2(ph, asH2(vb.x), acc[4]);
        acc[5] = fdot2(ph, asH2(vb.y), acc[5]);
        acc[6] = fdot2(ph, asH2(vb.z), acc[6]);
        acc[7] = fdot2(ph, asH2(vb.w), acc[7]);
    }

    // merge the block's 4 waves once via LDS (no atomics, no butterfly)
    #pragma unroll
    for (int c = 0; c < 8; c++) red[wv][lane][c] = acc[c];
    red[wv][lane][8] = l;
    __syncthreads();
    for (int e = tid; e < 576; e += 256) {
        const int r = e / 9, c = e - r * 9;
        const float s = red[0][r][c] + red[1][r][c] + red[2][r][c] + red[3][r][c];
        part[((size_t)chunk * 8192 + rgrp * 64 + r) * 9 + c] = s;
    }
}

__global__ __launch_bounds__(256) void finish_kernel(
    const float* __restrict__ x,
    const float* __restrict__ Zw, const float* __restrict__ Zb,
    const float* __restrict__ part, float* __restrict__ out, int nch)
{
    __shared__ float Zs[128 * 9];
    __shared__ float zw_s[384];
    __shared__ float zb_s[48];
    const int tid = threadIdx.x;
    const int r0 = blockIdx.x * 128;

    for (int i = tid; i < 384; i += 256) zw_s[i] = Zw[i];
    if (tid < 48) zb_s[tid] = Zb[tid];

    if (tid < 128) {
        const int row = r0 + tid;
        float a[9];
        #pragma unroll
        for (int c = 0; c < 9; c++) a[c] = 0.f;
        for (int ch = 0; ch < nch; ch++) {
            const float* p = part + ((size_t)ch * 8192 + row) * 9;
            #pragma unroll
            for (int c = 0; c < 9; c++) a[c] += p[c];
        }
        const float inv = 1.0f / a[8];
        #pragma unroll
        for (int c = 0; c < 8; c++) Zs[tid * 9 + c] = a[c] * inv;
    }
    __syncthreads();

    for (int e = tid; e < 128 * 48; e += 256) {
        const int r = e / 48, c = e - r * 48;
        float o = x[r0 * 48 + e] + zb_s[c];
        #pragma unroll
        for (int k = 0; k < 8; k++) o = fmaf(Zs[r * 9 + k], zw_s[k * 48 + c], o);
        out[r0 * 48 + e] = o;
    }
}

extern "C" void kernel_launch(void* const* d_in, const int* in_sizes, int n_in,
                              void* d_out, int out_size, void* d_ws, size_t ws_size,
                              hipStream_t stream) {
    const float* x  = (const float*)d_in[0];
    const float* Kw = (const float*)d_in[1];
    const float* Kb = (const float*)d_in[2];
    const float* Qw = (const float*)d_in[3];
    const float* Qb = (const float*)d_in[4];
    const float* Vw = (const float*)d_in[5];
    const float* Vb = (const float*)d_in[6];
    const float* Zw = (const float*)d_in[7];
    const float* Zb = (const float*)d_in[8];
    float* out = (float*)d_out;

    float* ws = (float*)d_ws;
    unsigned* Xksf16 = (unsigned*)ws;
    unsigned* QV     = (unsigned*)(ws + QV_OFF);
    unsigned int* qmax2_bits = (unsigned int*)(ws + QMAX_OFF);
    float* part = ws + PART_OFF;

    // pick largest chunk count that fits the workspace (deterministic per session)
    int nch = 16;
    const size_t avail = ws_size / 4;
    while (nch > 1 && (size_t)PART_OFF + (size_t)nch * 8192 * 9 > avail) nch >>= 1;
    const int ppw = 1024 / nch;   // j-pairs per wave (4096 pairs / (nch*4 waves))

    (void)hipMemsetAsync(qmax2_bits, 0, sizeof(unsigned int), stream);
    proj_kernel<<<256, 256, 0, stream>>>(x, Kw, Kb, Qw, Qb, Vw, Vb,
                                         Xksf16, QV, qmax2_bits);
    attn_kernel<<<128 * nch, 256, 0, stream>>>(Xksf16, QV, qmax2_bits, part, ppw);
    finish_kernel<<<64, 256, 0, stream>>>(x, Zw, Zb, part, out, nch);
}